// Round 2
// baseline (426.894 us; speedup 1.0000x reference)
//
#include <hip/hip_runtime.h>
#include <hip/hip_bf16.h>

#define MM 2048   // memory slots
#define BB 64     // batch
#define TT 4      // tokens per slot
#define DD 128    // embed dim
#define VV 50000  // vocab

// ---- zero u ----
__global__ void k_zero(float* __restrict__ u) {
    u[blockIdx.x * 256 + threadIdx.x] = 0.f;
}

// ---- scores: s[b,m] = sum_t (tok!=0) * dot(C[h][tok], u[b]) ----
// one wave per 16 consecutive m for a fixed b; lane owns dims 2*lane, 2*lane+1
__global__ void k_scores(const int* __restrict__ st,
                         const float* __restrict__ Ch,
                         const float* __restrict__ u,
                         float* __restrict__ s) {
    const int wid  = (blockIdx.x * 256 + threadIdx.x) >> 6;  // 8192 waves
    const int lane = threadIdx.x & 63;
    const int b    = wid >> 7;          // 128 waves per b
    const int m0   = (wid & 127) << 4;  // 16 m per wave

    const float2 ub = *(const float2*)(u + b * DD + 2 * lane);

    for (int mi = 0; mi < 16; ++mi) {
        const int m = m0 + mi;
        const int4 tk = *(const int4*)(st + (m * BB + b) * TT);
        const int toks[4] = {tk.x, tk.y, tk.z, tk.w};
        float acc = 0.f;
#pragma unroll
        for (int t = 0; t < 4; ++t) {
            const int tok = toks[t];
            if (tok != 0) {
                const float2 cf =
                    *(const float2*)(Ch + (size_t)tok * DD + 2 * lane);
                acc += cf.x * ub.x + cf.y * ub.y;
            }
        }
#pragma unroll
        for (int off = 32; off; off >>= 1) acc += __shfl_xor(acc, off, 64);
        if (lane == 0) s[b * MM + m] = acc;
    }
}

// ---- softmax over m (in place), one block per b ----
__global__ void k_softmax(float* __restrict__ s) {
    const int b = blockIdx.x;
    float* sb = s + b * MM;
    const int tid = threadIdx.x;  // 256
    __shared__ float redmax[4];
    __shared__ float redsum[4];

    float v[8];
    float mx = -1e30f;
#pragma unroll
    for (int i = 0; i < 8; ++i) {
        v[i] = sb[tid + 256 * i];
        mx = fmaxf(mx, v[i]);
    }
#pragma unroll
    for (int off = 32; off; off >>= 1) mx = fmaxf(mx, __shfl_xor(mx, off, 64));
    if ((tid & 63) == 0) redmax[tid >> 6] = mx;
    __syncthreads();
    const float gmax = fmaxf(fmaxf(redmax[0], redmax[1]),
                             fmaxf(redmax[2], redmax[3]));

    float sum = 0.f;
#pragma unroll
    for (int i = 0; i < 8; ++i) {
        v[i] = __expf(v[i] - gmax);
        sum += v[i];
    }
#pragma unroll
    for (int off = 32; off; off >>= 1) sum += __shfl_xor(sum, off, 64);
    if ((tid & 63) == 0) redsum[tid >> 6] = sum;
    __syncthreads();
    const float inv = 1.f / (redsum[0] + redsum[1] + redsum[2] + redsum[3]);
#pragma unroll
    for (int i = 0; i < 8; ++i) sb[tid + 256 * i] = v[i] * inv;
}

// ---- output: u[b,:] += sum_m prob[b,m] * sum_t (tok!=0) C[h+1][tok][:] ----
// one wave per 32 consecutive m for a fixed b; atomic fp32 accumulate into u
__global__ void k_output(const int* __restrict__ st,
                         const float* __restrict__ Ch,
                         const float* __restrict__ prob,
                         float* __restrict__ u) {
    const int wid  = (blockIdx.x * 256 + threadIdx.x) >> 6;  // 4096 waves
    const int lane = threadIdx.x & 63;
    const int b    = wid >> 6;          // 64 waves per b
    const int m0   = (wid & 63) << 5;   // 32 m per wave

    float ax = 0.f, ay = 0.f;
    for (int mi = 0; mi < 32; ++mi) {
        const int m = m0 + mi;
        const float p = prob[b * MM + m];
        const int4 tk = *(const int4*)(st + (m * BB + b) * TT);
        const int toks[4] = {tk.x, tk.y, tk.z, tk.w};
#pragma unroll
        for (int t = 0; t < 4; ++t) {
            const int tok = toks[t];
            if (tok != 0) {
                const float2 cf =
                    *(const float2*)(Ch + (size_t)tok * DD + 2 * lane);
                ax += p * cf.x;
                ay += p * cf.y;
            }
        }
    }
    atomicAdd(u + b * DD + 2 * lane, ax);
    atomicAdd(u + b * DD + 2 * lane + 1, ay);
}

// ---- copy u -> out (fp32) ----
__global__ void k_copy(const float* __restrict__ u, float* __restrict__ out) {
    const int i = blockIdx.x * 256 + threadIdx.x;
    out[i] = u[i];
}

extern "C" void kernel_launch(void* const* d_in, const int* in_sizes, int n_in,
                              void* d_out, int out_size, void* d_ws, size_t ws_size,
                              hipStream_t stream) {
    const int* st = (const int*)d_in[0];
    const float* C = (const float*)d_in[1];

    float* u = (float*)d_ws;                          // 64*128 fp32 = 32 KB
    float* s = (float*)((char*)d_ws + BB * DD * 4);   // 64*2048 fp32 = 512 KB

    k_zero<<<(BB * DD) / 256, 256, 0, stream>>>(u);

    for (int hop = 0; hop < 3; ++hop) {
        const float* Ch  = C + (size_t)hop * VV * DD;
        const float* Ch1 = C + (size_t)(hop + 1) * VV * DD;
        // 64 b * 128 waves, 4 waves/block -> 2048 blocks
        k_scores<<<2048, 256, 0, stream>>>(st, Ch, u, s);
        k_softmax<<<BB, 256, 0, stream>>>(s);
        // 64 b * 64 waves, 4 waves/block -> 1024 blocks
        k_output<<<1024, 256, 0, stream>>>(st, Ch1, s, u);
    }

    k_copy<<<(BB * DD) / 256, 256, 0, stream>>>(u, (float*)d_out);
}